// Round 11
// baseline (6839.717 us; speedup 1.0000x reference)
//
#include <hip/hip_runtime.h>
#include <math.h>

namespace {

constexpr int N_   = 200;   // nodes
constexpr int H_   = 20;    // inner steps
constexpr int B_   = 400;   // outer steps
constexpr int OUT_ = 64;    // eeg channels
constexpr int BUF_ = 500;   // hE buffer length
constexpr int NT_  = 1024;  // 16 waves, single persistent workgroup
constexpr int HD_  = 50;    // history depth (max delay 49)
constexpr int HS_  = 51;    // transposed history stride (histT[j*HS_+c])
constexpr int GT0  = 224;   // first gather thread (INIT phases only)
constexpr int NG_  = 800;   // gather units (4 per row)
constexpr int EPT  = 50;    // entries per gather unit
constexpr int CAP  = 16;    // CSR capacity (d==0 / d==1)
constexpr int UNR  = 12;    // unrolled CSR entries
constexpr int RW_  = 256;   // row-group threads (waves 0-3, lockstep)
constexpr int NFREE = NT_ - RW_;   // 768 free-running gather threads
constexpr int SLAB  = H_ * N_;     // 4000 slab elements

constexpr float L2E = 1.4426950408889634f;
constexpr float LN2 = 0.6931471805599453f;

constexpr float DT_  = 0.0001f;
constexpr float G_   = 1000.01f;
constexpr float C1_  = 135.01f;
constexpr float C2_  = 108.01f;
constexpr float C3_  = 33.76f;
constexpr float C4_  = 33.76f;
constexpr float STD_ = 250.0f;
constexpr float K_   = 5.5f;
constexpr float CY0_ = 5.0f;
constexpr float Y0_  = 2.0f;

constexpr float RL2E = 0.56f * L2E;
constexpr float V0R  = 6.0f * RL2E;
constexpr float TU_  = 2.0f * L2E / 500.0f;
constexpr float TS_  = 2.0f * L2E / 1000.0f;

// ddXv = Xv + DT*(A*a*u - 2a*Xv - a^2*X)
constexpr float KMv = 0.9798f, KMu = 0.0328250f, KMx = 1.0201f;
constexpr float KEv = 0.9798f, KEu = 0.0328250f, KEx = 1.0201f;
constexpr float KIv = 0.9898f, KIu = 0.1122000f, KIx = 0.2601f;

__device__ __forceinline__ float fexp2(float x){ return __builtin_amdgcn_exp2f(x); }
__device__ __forceinline__ float flog2(float x){ return __builtin_amdgcn_logf(x); }
__device__ __forceinline__ float frcp (float x){ return __builtin_amdgcn_rcpf(x); }

__device__ __forceinline__ float sigf(float x){
    return 5.0f * frcp(1.0f + fexp2(fmaf(-RL2E, x, V0R)));
}
__device__ __forceinline__ float tanh500(float x){
    return 500.0f - 1000.0f * frcp(1.0f + fexp2(x * TU_));
}
__device__ __forceinline__ float satf(float x){
    return 1000.0f - 2000.0f * frcp(1.0f + fexp2(x * TS_));
}
__device__ __forceinline__ float wl_f(const float* __restrict__ wbb,
                                      const float* __restrict__ sc,
                                      int i, int j){
    float w0 = fexp2(wbb[i*N_+j]*L2E) * sc[i*N_+j];
    float w1 = fexp2(wbb[j*N_+i]*L2E) * sc[j*N_+i];
    return flog2(1.0f + 0.5f*(w0+w1)) * LN2;
}

// R11 = R8 structure with __launch_bounds__(NT_, 1).
// R10 showed (NT_,4) did NOT lift the 64-VGPR cap (VGPR_Count still 64,
// WRITE_SIZE still ~795KB = spill persists): hipcc evidently treats the
// 2nd arg as CUDA-style min BLOCKS/CU, so "4" (=64 waves/CU, impossible)
// clamps back to 2 blocks/CU = 64-VGPR cap.  "(NT_,1)" yields the 128-VGPR
// cap under BOTH interpretations (1 block/CU = 16 waves; or 1 wave/EU).
// This is the first real test of the R8 pipeline: block {h,h+1} publishes
// (M(h+4),M(h+5)) into a 3-buffer rotation, each row prefetches the NEXT
// block's 12 CSR M-pairs into named registers mid-body (hidden under the
// transcendental chain), and ROW_SYNC's lgkmcnt(0) retires stragglers.
// Arithmetic identical to validated R8/R10 (absmax 0.8703499).
// Diagnostics: VGPR_Count must rise >64; WRITE_SIZE must fall to ~640KB.
// Decision rule: <5800 keep; ~5900-6100 or still-spilled -> R4 is the
// floor, declare roofline next round.
__global__ void __launch_bounds__(NT_, 1)
jansen_kernel(
    const float* __restrict__ input,     // (N,H,B)
    const float* __restrict__ noise_in,  // (N,H,B,3)
    const float* __restrict__ hx,        // (N,6)
    const float* __restrict__ hEin,      // (N,500)
    const float* __restrict__ wbb,       // (N,N)
    const float* __restrict__ lm,        // (64,N)
    const float* __restrict__ sc,        // (N,N)
    const int*   __restrict__ dist,      // (N,N)
    float* __restrict__ out,             // 64*400 eeg + N*6 state
    float2* __restrict__ tab)            // d_ws: 40000 x (w, meta)
{
    __shared__ float histT[N_*HS_];          // transposed circular M history
    __shared__ float uslab[H_*N_];           // u for current outer step
    __shared__ float neslab[H_*N_];          // noise for current outer step
    __shared__ float d0w_l[CAP*N_];          // d==0 CSR weights (SoA)
    __shared__ unsigned char d0j_l[CAP*N_];  // d==0 CSR j (u8)
    __shared__ float d1w_l[CAP*N_];          // d==1 CSR weights
    __shared__ unsigned char d1j_l[CAP*N_];  // d==1 CSR j
    __shared__ float led_part[4*N_];         // static-gather partials
    __shared__ float2 mtri[3*N_];            // 3-rotating (M(2p),M(2p+1)) bufs
    __shared__ float emi[N_];
    __shared__ float colmean[N_];
    __shared__ float lmrs[OUT_];
    __shared__ float red_s[NT_/64];
    __shared__ float norm_s;
    __shared__ int   rbar;                   // row-wave barrier counter

    const int t = threadIdx.x;
    const bool isr = (t < N_);
    const bool isg = (t >= GT0);             // init-phase gather role
    const int  gt  = t - GT0;                // init-phase unit id 0..799
    const int  grow  = gt >> 2;
    const int  gslot = gt & 3;
    const int  jbase = gslot * EPT;
    const int  tb    = gt * EPT;

    int sidx[5];                             // init slab LDS indices
    int goff[5];                             // init slab global offsets

    // ===== S0: lmrs + hist init + initial slab (b=0) =====
    if (t == 0) rbar = 0;
    if (t < OUT_){
        float s2 = 0.f;
        for (int j=0;j<N_;++j) s2 += fabsf(lm[t*N_+j]);
        lmrs[t] = s2;
    }
    float M=0,E=0,I=0,Mv=0,Ev=0,Iv=0, rowsum=0, ledst=0, hE0v=0;
    int cnt0=0, cnt1=0;
    #pragma unroll
    for (int r=0;r<5;++r){ sidx[r]=0; goff[r]=0; }
    if (isg){
        #pragma unroll
        for (int r=0;r<5;++r){
            int p = r*NG_ + gt;
            int hh = p / N_, ii = p - hh*N_;
            sidx[r] = hh*N_ + ii;
            goff[r] = ii*(H_*B_) + hh*B_;
            uslab[sidx[r]]  = input[goff[r]];
            neslab[sidx[r]] = noise_in[goff[r]*3];
        }
    }
    if (isr){
        // initial hEb col k (k=1..49) -> slot (0-k) mod 50 = 50-k
        for (int k=1;k<HD_;++k) histT[t*HS_ + (HD_-k)] = hEin[t*BUF_+k];
        hE0v = hEin[t*BUF_];                 // quirk: step (0,0) LEd source
        M=hx[t*6+0]; E=hx[t*6+1]; I=hx[t*6+2];
        Mv=hx[t*6+3]; Ev=hx[t*6+4]; Iv=hx[t*6+5];
    }
    __syncthreads();

    // ===== S1: compute wl entries -> RAW table; Frobenius + rowsum =====
    float ss = 0.f, rs = 0.f;
    for (int m=0;m<EPT;++m){
        float w = 0.f; int d = 2;
        int j = jbase + m;
        if (isg){
            d = dist[j*N_+grow] >> 1;        // delays[j][grow]
            w = wl_f(wbb, sc, grow, j);
        }
        ss = fmaf(w,w,ss); rs += w;
        if (isg){
            int dm = (d<2) ? 2 : d;          // d<2 handled by CSRs
            float ws = (d>=2) ? w : 0.f;
            tab[tb+m] = make_float2(ws, __uint_as_float((unsigned)j | ((unsigned)dm<<16)));
        }
    }
    if (isr){                                 // colmean (needs lmrs)
        float cm=0.f;
        for (int o=0;o<OUT_;++o) cm += lm[o*N_+t] * frcp(lmrs[o]);
        colmean[t] = cm * (1.0f/(float)OUT_);
    }
    #pragma unroll
    for (int o=32;o>0;o>>=1) ss += __shfl_down(ss,o,64);
    if ((t&63)==0) red_s[t>>6] = ss;
    __syncthreads();
    if (t==0){ float tot=0.f; for (int w=0;w<NT_/64;++w) tot+=red_s[w]; norm_s = sqrtf(tot); }
    __syncthreads();
    const float inv = 1.0f / norm_s;
    // fixup: normalize table weights in place
    if (isg){
        float* tf = (float*)tab;
        for (int m=0;m<EPT;++m) tf[2*(tb+m)] *= inv;
    }
    if (isg) led_part[gslot*N_+grow] = rs;    // raw rowsum partial

    // ===== S3: row CSR build (d<2), registers for d0 =====
    float dw[UNR]; unsigned jpk[3];
    #pragma unroll
    for (int k=0;k<UNR;++k) dw[k] = 0.f;
    jpk[0]=jpk[1]=jpk[2]=0u;
    if (isr){
        #pragma unroll
        for (int k=0;k<UNR;++k){ d0w_l[k*N_+t]=0.f; d0j_l[k*N_+t]=0;
                                 d1w_l[k*N_+t]=0.f; d1j_l[k*N_+t]=0; }
        for (int j=0;j<N_;++j){
            int dd = dist[j*N_+t] >> 1;
            if (dd < 2){
                float w = wl_f(wbb, sc, t, j) * inv;
                if (dd==0){ if (cnt0<CAP){ d0w_l[cnt0*N_+t]=w; d0j_l[cnt0*N_+t]=(unsigned char)j; ++cnt0; } }
                else      { if (cnt1<CAP){ d1w_l[cnt1*N_+t]=w; d1j_l[cnt1*N_+t]=(unsigned char)j; ++cnt1; } }
            }
        }
        #pragma unroll
        for (int k=0;k<UNR;++k){
            dw[k] = d0w_l[k*N_+t];
            unsigned jv = d0j_l[k*N_+t];
            jpk[k>>2] |= jv << ((k&3)*8);
        }
    }
    __syncthreads();

    // ===== S4: rowsum =====
    if (isr){
        rowsum = (led_part[t]+led_part[N_+t]+led_part[2*N_+t]+led_part[3*N_+t]) * inv;
    }
    __syncthreads();

    // ===== S5: initial static gather for s=0 (target step 0 -> c = 50-d) =====
    if (isg){
        float a0 = 0.f;
        for (int m=0;m<EPT;++m){
            float2 e = tab[tb+m];
            unsigned um = __float_as_uint(e.y);
            int c = HD_ - (int)(um>>16);     // d in [2,49] -> c in [1,48]
            a0 = fmaf(e.x, histT[(um&0xFFFFu)*HS_ + c], a0);
        }
        led_part[gslot*N_+grow] = a0;
    }
    __syncthreads();

    // ===== S6: initial ledst (+ d==1 from hE col 1 = slot 49) =====
    if (isr){
        float v = led_part[t]+led_part[N_+t]+led_part[2*N_+t]+led_part[3*N_+t];
        #pragma unroll
        for (int k=0;k<UNR;++k)
            v = fmaf(d1w_l[k*N_+t], histT[(int)d1j_l[k*N_+t]*HS_ + 49], v);
        for (int k=UNR;k<cnt1;++k)
            v = fmaf(d1w_l[k*N_+t], histT[(int)d1j_l[k*N_+t]*HS_ + 49], v);
        ledst = v;
    }

    // ===== main-loop free-thread mapping (units + slab staging) =====
    const int gf = t - RW_;                  // 0..767 for free threads
    int sidxM[6], goffM[6];
    bool has6 = false;
    if (t >= RW_){
        #pragma unroll
        for (int r=0;r<6;++r){
            int p = r*NFREE + gf;
            if (p < SLAB){
                int hh = p / N_, ii = p - hh*N_;
                sidxM[r] = hh*N_ + ii;
                goffM[r] = ii*(H_*B_) + hh*B_;
            } else { sidxM[r]=0; goffM[r]=0; }
        }
        has6 = (5*NFREE + gf) < SLAB;        // gf < 160
    }

    // ===== prologue: steps {0,1} M-side + one-ahead E/I, publish buf0/buf1 =====
    // Carries entering block p (steps h=2p, h+1):
    //   E0=E(h) E1c=E(h+1) Ev0=Ev(h) | I0,I1c,Iv0 |
    //   M0=M(h) M1=M(h+1) M2c=M(h+2) M3c=M(h+3) Mv2c=Mv(h+2)
    float E1c=0, I1c=0, M1=0, M2c=0, M3c=0, Mv2c=0, MvOut=Mv;
    if (isr){
        E1c = satf(fmaf(DT_, Ev, E));        // E(1)
        I1c = satf(fmaf(DT_, Iv, I));        // I(1)
        float uM0 = tanh500(sigf(E - I));    // rM(0)
        float Mv1 = satf(fmaf(KMv, Mv, fmaf(KMu, uM0, -KMx*M)));
        M1  = satf(fmaf(DT_, Mv, M));        // M(1)
        float uM1 = tanh500(sigf(E1c - I1c));
        Mv2c = satf(fmaf(KMv, Mv1, fmaf(KMu, uM1, -KMx*M1)));
        M2c  = satf(fmaf(DT_, Mv1, M1));     // M(2)
        M3c  = satf(fmaf(DT_, Mv2c, M2c));   // M(3)
        mtri[t]      = make_float2(hE0v, M1);   // buf0: (col0@s0, M(1)) quirk
        mtri[N_ + t] = make_float2(M2c, M3c);   // buf1: (M(2), M(3))
    }
    __syncthreads();

    // prefetch block-0 operands from buf0 into registers
    float2 pf[UNR];
    #pragma unroll
    for (int k=0;k<UNR;++k) pf[k] = make_float2(0.f,0.f);
    if (isr){
        #pragma unroll
        for (int k=0;k<UNR;++k){
            int j = (jpk[k>>2] >> ((k&3)*8)) & 255;
            pf[k] = mtri[j];
        }
    }

// 4-wave row barrier: drain own LDS ops, count in, spin to epoch target
#define ROW_SYNC()                                                           \
    do {                                                                     \
        asm volatile("s_waitcnt lgkmcnt(0)" ::: "memory");                   \
        if ((t & 63) == 0) atomicAdd(&rbar, 1);                              \
        ++repoch;                                                            \
        while (*(volatile int*)&rbar < 4*repoch)                             \
            __builtin_amdgcn_s_sleep(1);                                     \
        asm volatile("" ::: "memory");                                       \
    } while(0)

    // ===== main loop: 400 outer x (10 blocks of 2 pipelined inner steps) =====
    int smod = 0;
    int repoch = 0;
    int cr = 0;                               // read-buffer index (block p%3)
    float su_r[6], sn_r[6];
    for (int s=0; s<B_; ++s){
        int ts = smod+1; if (ts==HD_) ts = 0;      // (s+1) % 50
        if (t < RW_){
            // ---- row waves: 10 blocks, one 4-wave sync per block ----
            #pragma unroll 1
            for (int kb=0; kb<10; ++kb){
                int pre = cr+1; if (pre==3) pre = 0;
                int wbx = pre+1; if (wbx==3) wbx = 0;
                if (isr){
                    float2* wb = mtri + wbx*N_;
                    // d0 gather from PREFETCHED registers (buf cr data)
                    float g0=ledst, g1=0.f, g2=0.f, g3=0.f;   // step h
                    float f0=ledst, f1=0.f, f2=0.f, f3=0.f;   // step h+1
                    #pragma unroll
                    for (int k=0;k<UNR;++k){
                        float2 mj = pf[k];
                        float w = dw[k];
                        if      ((k&3)==0){ g0=fmaf(w,mj.x,g0); f0=fmaf(w,mj.y,f0); }
                        else if ((k&3)==1){ g1=fmaf(w,mj.x,g1); f1=fmaf(w,mj.y,f1); }
                        else if ((k&3)==2){ g2=fmaf(w,mj.x,g2); f2=fmaf(w,mj.y,f2); }
                        else              { g3=fmaf(w,mj.x,g3); f3=fmaf(w,mj.y,f3); }
                    }
                    for (int k=UNR;k<cnt0;++k){
                        float w = d0w_l[k*N_+t];
                        float2 mj = mtri[cr*N_ + d0j_l[k*N_+t]];
                        g0=fmaf(w,mj.x,g0); f0=fmaf(w,mj.y,f0);
                    }
                    // issue prefetch for NEXT block (buf pre), hidden under
                    // the transcendental chains below
                    #pragma unroll
                    for (int k=0;k<UNR;++k){
                        int j = (jpk[k>>2] >> ((k&3)*8)) & 255;
                        pf[k] = mtri[pre*N_ + j];
                    }
                    float LEd0 = (g0+g1)+(g2+g3);
                    float LEd1 = (f0+f1)+(f2+f3);
                    MvOut = Mv2c;                 // Mv(h+2): final Mv(8000)
                    // E chain, step h
                    int h0 = 2*kb;
                    float u0  = uslab[h0*N_+t];
                    float ne0 = neslab[h0*N_+t];
                    float rE0 = fmaf(STD_, ne0, G_*(LEd0 - rowsum*E)) + C2_*sigf(C1_*M);
                    float uE0 = fmaf(K_, u0, tanh500(rE0));
                    float Ev1 = satf(fmaf(KEv, Ev, fmaf(KEu, uE0, -KEx*E)));
                    float E2  = satf(fmaf(DT_, Ev1, E1c));
                    // I chain, step h
                    float uI0 = tanh500(C4_*sigf(C3_*M));
                    float Iv1 = satf(fmaf(KIv, Iv, fmaf(KIu, uI0, -KIx*I)));
                    float I2  = satf(fmaf(DT_, Iv1, I1c));
                    // E chain, step h+1
                    float u1  = uslab[(h0+1)*N_+t];
                    float ne1 = neslab[(h0+1)*N_+t];
                    float rE1 = fmaf(STD_, ne1, G_*(LEd1 - rowsum*E1c)) + C2_*sigf(C1_*M1);
                    float uE1 = fmaf(K_, u1, tanh500(rE1));
                    float Ev2 = satf(fmaf(KEv, Ev1, fmaf(KEu, uE1, -KEx*E1c)));
                    float E3n = satf(fmaf(DT_, Ev2, E2));
                    // I chain, step h+1
                    float uI1 = tanh500(C4_*sigf(C3_*M1));
                    float Iv2 = satf(fmaf(KIv, Iv1, fmaf(KIu, uI1, -KIx*I1c)));
                    float I3n = satf(fmaf(DT_, Iv2, I2));
                    // M chain (+2 ahead): publish (M(h+4), M(h+5))
                    float uM2 = tanh500(sigf(E2 - I2));
                    float Mv3 = satf(fmaf(KMv, Mv2c, fmaf(KMu, uM2, -KMx*M2c)));
                    float M4  = satf(fmaf(DT_, Mv3, M3c));
                    float uM3 = tanh500(sigf(E3n - I3n));
                    float Mv4 = satf(fmaf(KMv, Mv3, fmaf(KMu, uM3, -KMx*M3c)));
                    float M5  = satf(fmaf(DT_, Mv4, M4));
                    wb[t] = make_float2(M4, M5);
                    // rotate carries
                    E=E2; E1c=E3n; Ev=Ev2;
                    I=I2; I1c=I3n; Iv=Iv2;
                    M=M2c; M1=M3c; M2c=M4; M3c=M5; Mv2c=Mv4;
                }
                cr = pre;
                // last sync per outer dropped: boundary __syncthreads orders
                // block 9's reads/writes before next outer's accesses.
                if (kb < 9) ROW_SYNC();
            }
            if (isr){ histT[t*HS_ + smod] = M; emi[t] = E - I; }
        } else {
            // ---- free gather waves: flat 50-entry gather, no step sync ----
            cr += 10; cr %= 3;                             // advance like rows
            float acc = 0.f;
            {
                const float4* t4 = (const float4*)(tab + (size_t)gf*EPT);
                #pragma unroll 5
                for (int m=0;m<EPT/2;++m){
                    float4 ee = t4[m];
                    unsigned um0 = __float_as_uint(ee.y);
                    int c0 = ts - (int)(um0>>16); if (c0<0) c0 += HD_;
                    acc = fmaf(ee.x, histT[(um0&0xFFFFu)*HS_ + c0], acc);
                    unsigned um1 = __float_as_uint(ee.w);
                    int c1 = ts - (int)(um1>>16); if (c1<0) c1 += HD_;
                    acc = fmaf(ee.z, histT[(um1&0xFFFFu)*HS_ + c1], acc);
                }
            }
            led_part[(gf&3)*N_ + (gf>>2)] = acc;
            if (gf < NG_-NFREE){                    // 32 threads: 2nd unit
                const int u1 = NFREE + gf;
                float acc1 = 0.f;
                const float4* t4 = (const float4*)(tab + (size_t)u1*EPT);
                #pragma unroll 5
                for (int m=0;m<EPT/2;++m){
                    float4 ee = t4[m];
                    unsigned um0 = __float_as_uint(ee.y);
                    int c0 = ts - (int)(um0>>16); if (c0<0) c0 += HD_;
                    acc1 = fmaf(ee.x, histT[(um0&0xFFFFu)*HS_ + c0], acc1);
                    unsigned um1 = __float_as_uint(ee.w);
                    int c1 = ts - (int)(um1>>16); if (c1<0) c1 += HD_;
                    acc1 = fmaf(ee.z, histT[(um1&0xFFFFu)*HS_ + c1], acc1);
                }
                led_part[(u1&3)*N_ + (u1>>2)] = acc1;
            }
            // slab loads for s+1 into registers (LDS write deferred past A)
            int sn = s+1; if (sn >= B_) sn = B_-1;
            #pragma unroll
            for (int r=0;r<5;++r){
                su_r[r] = input[goffM[r] + sn];
                sn_r[r] = noise_in[(goffM[r] + sn)*3];
            }
            if (has6){
                su_r[5] = input[goffM[5] + sn];
                sn_r[5] = noise_in[(goffM[5] + sn)*3];
            }
        }
        __syncthreads();                            // boundary A
        if (isr){
            // d==1 term for s+1: M_end(s) = .x of buf[cr] (written by block
            // 10s+8, drained at its ROW_SYNC; cr == (s+1)%3 here)
            float v = led_part[t]+led_part[N_+t]+led_part[2*N_+t]+led_part[3*N_+t];
            #pragma unroll
            for (int k=0;k<UNR;++k)
                v = fmaf(d1w_l[k*N_+t], mtri[cr*N_ + d1j_l[k*N_+t]].x, v);
            for (int k=UNR;k<cnt1;++k)
                v = fmaf(d1w_l[k*N_+t], mtri[cr*N_ + d1j_l[k*N_+t]].x, v);
            ledst = v;
        }
        if (t >= RW_){
            // slab LDS writes AFTER A (rows done reading slab for s)
            #pragma unroll
            for (int r=0;r<5;++r){
                uslab[sidxM[r]]  = su_r[r];
                neslab[sidxM[r]] = sn_r[r];
            }
            if (has6){ uslab[sidxM[5]] = su_r[5]; neslab[sidxM[5]] = sn_r[5]; }
        }
        {   // eeg (all threads)
            int o = t>>4, l = t&15;
            float il = frcp(lmrs[o]);
            float a2 = 0.f;
            for (int j=l;j<N_;j+=16)
                a2 = fmaf(fmaf(lm[o*N_+j], il, -colmean[j]), emi[j], a2);
            a2 += __shfl_down(a2,8,16); a2 += __shfl_down(a2,4,16);
            a2 += __shfl_down(a2,2,16); a2 += __shfl_down(a2,1,16);
            if (l==0) out[o*B_+s] = fmaf(CY0_, a2, -Y0_);
        }
        smod = ts;
        __syncthreads();                            // boundary B
    }

#undef ROW_SYNC

    // final state: carries are exactly state(8000); Mv via MvOut=Mv(8000)
    if (isr){
        float* cs = out + OUT_*B_ + t*6;
        cs[0]=M; cs[1]=E; cs[2]=I; cs[3]=MvOut; cs[4]=Ev; cs[5]=Iv;
    }
}

} // namespace

extern "C" void kernel_launch(void* const* d_in, const int* in_sizes, int n_in,
                              void* d_out, int out_size, void* d_ws, size_t ws_size,
                              hipStream_t stream)
{
    const float* input    = (const float*)d_in[0];
    const float* noise_in = (const float*)d_in[1];
    const float* hx   = (const float*)d_in[3];
    const float* hEin = (const float*)d_in[4];
    const float* wbb  = (const float*)d_in[5];
    const float* lm   = (const float*)d_in[6];
    const float* sc   = (const float*)d_in[7];
    const int*   dist = (const int*)d_in[8];
    float* out = (float*)d_out;
    float2* tab = (float2*)((char*)d_ws + 1024);   // 40000 x 8B = 320KB

    hipLaunchKernelGGL(jansen_kernel, dim3(1), dim3(NT_), 0, stream,
                       input, noise_in, hx, hEin, wbb, lm, sc, dist, out, tab);
}

// Round 12
// 5920.923 us; speedup vs baseline: 1.1552x; 1.1552x over previous
//
#include <hip/hip_runtime.h>
#include <math.h>

namespace {

constexpr int N_   = 200;   // nodes
constexpr int H_   = 20;    // inner steps
constexpr int B_   = 400;   // outer steps
constexpr int OUT_ = 64;    // eeg channels
constexpr int BUF_ = 500;   // hE buffer length
constexpr int NT_  = 1024;  // 16 waves, single persistent workgroup
constexpr int HD_  = 50;    // history depth (max delay 49)
constexpr int HS_  = 51;    // transposed history stride (histT[j*HS_+c])
constexpr int GT0  = 224;   // first gather thread (INIT phases only)
constexpr int NG_  = 800;   // gather units (4 per row)
constexpr int EPT  = 50;    // entries per gather unit
constexpr int CAP  = 16;    // CSR capacity (d==0 / d==1)
constexpr int UNR  = 12;    // unrolled CSR entries
constexpr int RW_  = 256;   // row-group threads (waves 0-3, lockstep)
constexpr int NFREE = NT_ - RW_;   // 768 free-running gather threads
constexpr int SLAB  = H_ * N_;     // 4000 slab elements

constexpr float L2E = 1.4426950408889634f;
constexpr float LN2 = 0.6931471805599453f;

constexpr float DT_  = 0.0001f;
constexpr float G_   = 1000.01f;
constexpr float C1_  = 135.01f;
constexpr float C2_  = 108.01f;
constexpr float C3_  = 33.76f;
constexpr float C4_  = 33.76f;
constexpr float STD_ = 250.0f;
constexpr float K_   = 5.5f;
constexpr float CY0_ = 5.0f;
constexpr float Y0_  = 2.0f;

constexpr float RL2E = 0.56f * L2E;
constexpr float V0R  = 6.0f * RL2E;
constexpr float TU_  = 2.0f * L2E / 500.0f;
constexpr float TS_  = 2.0f * L2E / 1000.0f;

// ddXv = Xv + DT*(A*a*u - 2a*Xv - a^2*X)
constexpr float KMv = 0.9798f, KMu = 0.0328250f, KMx = 1.0201f;
constexpr float KEv = 0.9798f, KEu = 0.0328250f, KEx = 1.0201f;
constexpr float KIv = 0.9898f, KIu = 0.1122000f, KIx = 0.2601f;

__device__ __forceinline__ float fexp2(float x){ return __builtin_amdgcn_exp2f(x); }
__device__ __forceinline__ float flog2(float x){ return __builtin_amdgcn_logf(x); }
__device__ __forceinline__ float frcp (float x){ return __builtin_amdgcn_rcpf(x); }

__device__ __forceinline__ float sigf(float x){
    return 5.0f * frcp(1.0f + fexp2(fmaf(-RL2E, x, V0R)));
}
__device__ __forceinline__ float tanh500(float x){
    return 500.0f - 1000.0f * frcp(1.0f + fexp2(x * TU_));
}
__device__ __forceinline__ float satf(float x){
    return 1000.0f - 2000.0f * frcp(1.0f + fexp2(x * TS_));
}
__device__ __forceinline__ float wl_f(const float* __restrict__ wbb,
                                      const float* __restrict__ sc,
                                      int i, int j){
    float w0 = fexp2(wbb[i*N_+j]*L2E) * sc[i*N_+j];
    float w1 = fexp2(wbb[j*N_+i]*L2E) * sc[j*N_+i];
    return flog2(1.0f + 0.5f*(w0+w1)) * LN2;
}

// R12 = REVERT to R4, the validated best (5923/5937us, absmax 0.8703499).
// Session ledger (all bit-exact): R2's 16->4-wave sync split was the one
// win (-660us).  Falsified levers: 4-step fusion (R1 +900), chain split
// (R3 +1130), barrier count /2 (R4 +-0), row TLP (R5 +2300), NT=512/128VGPR
// (R6 +3900), idle-clock theory (R7: heaters ran, dur unchanged), register
// prefetch (R8/R10/R11 +900: compiler pins VGPR=64 under every
// __launch_bounds__ spelling; pf[] spills to scratch).  Surviving model:
// the grind is a serial chain of ~1700cy/step -- 24 quarter-rate wave64
// transcendentals + LDS round-trip + barrier wake -- reducible by none of
// {sync width, barrier count, ILP, TLP, registers, clock}.  The remaining
// gap is algorithmic (fewer transcendentals per step), outside
// bit-compatible scope.  This kernel is the practical floor.
__global__ void __launch_bounds__(NT_)
jansen_kernel(
    const float* __restrict__ input,     // (N,H,B)
    const float* __restrict__ noise_in,  // (N,H,B,3)
    const float* __restrict__ hx,        // (N,6)
    const float* __restrict__ hEin,      // (N,500)
    const float* __restrict__ wbb,       // (N,N)
    const float* __restrict__ lm,        // (64,N)
    const float* __restrict__ sc,        // (N,N)
    const int*   __restrict__ dist,      // (N,N)
    float* __restrict__ out,             // 64*400 eeg + N*6 state
    float2* __restrict__ tab)            // d_ws: 40000 x (w, meta)
{
    __shared__ float histT[N_*HS_];          // transposed circular M history
    __shared__ float uslab[H_*N_];           // u for current outer step
    __shared__ float neslab[H_*N_];          // noise for current outer step
    __shared__ float d0w_l[CAP*N_];          // d==0 CSR weights (SoA)
    __shared__ unsigned char d0j_l[CAP*N_];  // d==0 CSR j (u8)
    __shared__ float d1w_l[CAP*N_];          // d==1 CSR weights
    __shared__ unsigned char d1j_l[CAP*N_];  // d==1 CSR j
    __shared__ float led_part[4*N_];         // static-gather partials
    __shared__ float2 mpair[2*N_];           // double-buffered (M(h),M(h+1))
    __shared__ float emi[N_];
    __shared__ float colmean[N_];
    __shared__ float lmrs[OUT_];
    __shared__ float red_s[NT_/64];
    __shared__ float norm_s;
    __shared__ int   rbar;                   // row-wave barrier counter

    const int t = threadIdx.x;
    const bool isr = (t < N_);
    const bool isg = (t >= GT0);             // init-phase gather role
    const int  gt  = t - GT0;                // init-phase unit id 0..799
    const int  grow  = gt >> 2;
    const int  gslot = gt & 3;
    const int  jbase = gslot * EPT;
    const int  tb    = gt * EPT;

    int sidx[5];                             // init slab LDS indices
    int goff[5];                             // init slab global offsets

    // ===== S0: lmrs + hist init + initial slab (b=0) =====
    if (t == 0) rbar = 0;
    if (t < OUT_){
        float s2 = 0.f;
        for (int j=0;j<N_;++j) s2 += fabsf(lm[t*N_+j]);
        lmrs[t] = s2;
    }
    float M=0,E=0,I=0,Mv=0,Ev=0,Iv=0, rowsum=0, ledst=0, hE0v=0;
    int cnt0=0, cnt1=0;
    #pragma unroll
    for (int r=0;r<5;++r){ sidx[r]=0; goff[r]=0; }
    if (isg){
        #pragma unroll
        for (int r=0;r<5;++r){
            int p = r*NG_ + gt;
            int hh = p / N_, ii = p - hh*N_;
            sidx[r] = hh*N_ + ii;
            goff[r] = ii*(H_*B_) + hh*B_;
            uslab[sidx[r]]  = input[goff[r]];
            neslab[sidx[r]] = noise_in[goff[r]*3];
        }
    }
    if (isr){
        // initial hEb col k (k=1..49) -> slot (0-k) mod 50 = 50-k
        for (int k=1;k<HD_;++k) histT[t*HS_ + (HD_-k)] = hEin[t*BUF_+k];
        hE0v = hEin[t*BUF_];                 // quirk: step (0,0) LEd source
        M=hx[t*6+0]; E=hx[t*6+1]; I=hx[t*6+2];
        Mv=hx[t*6+3]; Ev=hx[t*6+4]; Iv=hx[t*6+5];
    }
    __syncthreads();

    // ===== S1: compute wl entries -> RAW table; Frobenius + rowsum =====
    float ss = 0.f, rs = 0.f;
    for (int m=0;m<EPT;++m){
        float w = 0.f; int d = 2;
        int j = jbase + m;
        if (isg){
            d = dist[j*N_+grow] >> 1;        // delays[j][grow]
            w = wl_f(wbb, sc, grow, j);
        }
        ss = fmaf(w,w,ss); rs += w;
        if (isg){
            int dm = (d<2) ? 2 : d;          // d<2 handled by CSRs
            float ws = (d>=2) ? w : 0.f;
            tab[tb+m] = make_float2(ws, __uint_as_float((unsigned)j | ((unsigned)dm<<16)));
        }
    }
    if (isr){                                 // colmean (needs lmrs)
        float cm=0.f;
        for (int o=0;o<OUT_;++o) cm += lm[o*N_+t] * frcp(lmrs[o]);
        colmean[t] = cm * (1.0f/(float)OUT_);
    }
    #pragma unroll
    for (int o=32;o>0;o>>=1) ss += __shfl_down(ss,o,64);
    if ((t&63)==0) red_s[t>>6] = ss;
    __syncthreads();
    if (t==0){ float tot=0.f; for (int w=0;w<NT_/64;++w) tot+=red_s[w]; norm_s = sqrtf(tot); }
    __syncthreads();
    const float inv = 1.0f / norm_s;
    // fixup: normalize table weights in place
    if (isg){
        float* tf = (float*)tab;
        for (int m=0;m<EPT;++m) tf[2*(tb+m)] *= inv;
    }
    if (isg) led_part[gslot*N_+grow] = rs;    // raw rowsum partial

    // ===== S3: row CSR build (d<2), registers for d0 =====
    float dw[UNR]; unsigned jpk[3];
    #pragma unroll
    for (int k=0;k<UNR;++k) dw[k] = 0.f;
    jpk[0]=jpk[1]=jpk[2]=0u;
    if (isr){
        #pragma unroll
        for (int k=0;k<UNR;++k){ d0w_l[k*N_+t]=0.f; d0j_l[k*N_+t]=0;
                                 d1w_l[k*N_+t]=0.f; d1j_l[k*N_+t]=0; }
        for (int j=0;j<N_;++j){
            int dd = dist[j*N_+t] >> 1;
            if (dd < 2){
                float w = wl_f(wbb, sc, t, j) * inv;
                if (dd==0){ if (cnt0<CAP){ d0w_l[cnt0*N_+t]=w; d0j_l[cnt0*N_+t]=(unsigned char)j; ++cnt0; } }
                else      { if (cnt1<CAP){ d1w_l[cnt1*N_+t]=w; d1j_l[cnt1*N_+t]=(unsigned char)j; ++cnt1; } }
            }
        }
        #pragma unroll
        for (int k=0;k<UNR;++k){
            dw[k] = d0w_l[k*N_+t];
            unsigned jv = d0j_l[k*N_+t];
            jpk[k>>2] |= jv << ((k&3)*8);
        }
    }
    __syncthreads();

    // ===== S4: rowsum =====
    if (isr){
        rowsum = (led_part[t]+led_part[N_+t]+led_part[2*N_+t]+led_part[3*N_+t]) * inv;
    }
    __syncthreads();

    // ===== S5: initial static gather for s=0 (target step 0 -> c = 50-d) =====
    if (isg){
        float a0 = 0.f;
        for (int m=0;m<EPT;++m){
            float2 e = tab[tb+m];
            unsigned um = __float_as_uint(e.y);
            int c = HD_ - (int)(um>>16);     // d in [2,49] -> c in [1,48]
            a0 = fmaf(e.x, histT[(um&0xFFFFu)*HS_ + c], a0);
        }
        led_part[gslot*N_+grow] = a0;
    }
    __syncthreads();

    // ===== S6: initial ledst (+ d==1 from hE col 1 = slot 49) =====
    if (isr){
        float v = led_part[t]+led_part[N_+t]+led_part[2*N_+t]+led_part[3*N_+t];
        #pragma unroll
        for (int k=0;k<UNR;++k)
            v = fmaf(d1w_l[k*N_+t], histT[(int)d1j_l[k*N_+t]*HS_ + 49], v);
        for (int k=UNR;k<cnt1;++k)
            v = fmaf(d1w_l[k*N_+t], histT[(int)d1j_l[k*N_+t]*HS_ + 49], v);
        ledst = v;
    }

    // ===== main-loop free-thread mapping (units + slab staging) =====
    const int gf = t - RW_;                  // 0..767 for free threads
    int sidxM[6], goffM[6];
    bool has6 = false;
    if (t >= RW_){
        #pragma unroll
        for (int r=0;r<6;++r){
            int p = r*NFREE + gf;
            if (p < SLAB){
                int hh = p / N_, ii = p - hh*N_;
                sidxM[r] = hh*N_ + ii;
                goffM[r] = ii*(H_*B_) + hh*B_;
            } else { sidxM[r]=0; goffM[r]=0; }
        }
        has6 = (5*NFREE + gf) < SLAB;        // gf < 160
    }

    // ===== prologue: block-pipeline carries + first pair publication =====
    // Carries entering block {h,h+1}: E,Ev,I,Iv,Mv at h; M0=M(h); M1=M(h+1).
    float M1r = 0.f;
    if (isr){
        M1r = satf(fmaf(DT_, Mv, M));        // M(1), local lookahead
        // block 0 reads (col0-at-step0, col0-at-step1) = (hE[:,0], M(1))
        mpair[t] = make_float2(hE0v, M1r);
    }
    __syncthreads();

// 4-wave row barrier: drain own LDS ops, count in, spin to epoch target
#define ROW_SYNC()                                                           \
    do {                                                                     \
        asm volatile("s_waitcnt lgkmcnt(0)" ::: "memory");                   \
        if ((t & 63) == 0) atomicAdd(&rbar, 1);                              \
        ++repoch;                                                            \
        while (*(volatile int*)&rbar < 4*repoch)                             \
            __builtin_amdgcn_s_sleep(1);                                     \
        asm volatile("" ::: "memory");                                       \
    } while(0)

    // ===== main loop: 400 outer x (10 blocks of 2 pipelined inner steps) =====
    int smod = 0;
    int repoch = 0;
    float su_r[6], sn_r[6];
    for (int s=0; s<B_; ++s){
        int ts = smod+1; if (ts==HD_) ts = 0;      // (s+1) % 50
        if (t < RW_){
            // ---- row waves: 10 blocks, one 4-wave sync per block ----
            #pragma unroll 1
            for (int kb=0; kb<10; ++kb){
                if (isr){
                    const float2* rb = mpair + (kb&1)*N_;     // (M(h),M(h+1))
                    float2*       wb = mpair + ((kb+1)&1)*N_;
                    // d0 gather, both steps from one b64 pair read.
                    // Partial order per step identical to R2's l0..l3.
                    float g0=ledst, g1=0.f, g2=0.f, g3=0.f;   // step h
                    float f0=ledst, f1=0.f, f2=0.f, f3=0.f;   // step h+1
                    #pragma unroll
                    for (int k=0;k<UNR;++k){
                        int j = (jpk[k>>2] >> ((k&3)*8)) & 255;
                        float2 mj = rb[j];
                        float w = dw[k];
                        if      ((k&3)==0){ g0=fmaf(w,mj.x,g0); f0=fmaf(w,mj.y,f0); }
                        else if ((k&3)==1){ g1=fmaf(w,mj.x,g1); f1=fmaf(w,mj.y,f1); }
                        else if ((k&3)==2){ g2=fmaf(w,mj.x,g2); f2=fmaf(w,mj.y,f2); }
                        else              { g3=fmaf(w,mj.x,g3); f3=fmaf(w,mj.y,f3); }
                    }
                    for (int k=UNR;k<cnt0;++k){
                        float w = d0w_l[k*N_+t];
                        float2 mj = rb[d0j_l[k*N_+t]];
                        g0=fmaf(w,mj.x,g0); f0=fmaf(w,mj.y,f0);
                    }
                    float LEd0 = (g0+g1)+(g2+g3);
                    float LEd1 = (f0+f1)+(f2+f3);
                    // local E(h+1), I(h+1)
                    float E1s = satf(fmaf(DT_, Ev, E));
                    float I1s = satf(fmaf(DT_, Iv, I));
                    // M lookahead chain: publish (M(h+2), M(h+3))
                    float uM0 = tanh500(sigf(E - I));
                    float Mv1 = satf(fmaf(KMv, Mv, fmaf(KMu, uM0, -KMx*M)));
                    float M2  = satf(fmaf(DT_, Mv1, M1r));
                    float uM1 = tanh500(sigf(E1s - I1s));
                    float Mv2 = satf(fmaf(KMv, Mv1, fmaf(KMu, uM1, -KMx*M1r)));
                    float M3  = satf(fmaf(DT_, Mv2, M2));
                    wb[t] = make_float2(M2, M3);
                    // I chain
                    float uI0 = tanh500(C4_*sigf(C3_*M));
                    float Iv1 = satf(fmaf(KIv, Iv, fmaf(KIu, uI0, -KIx*I)));
                    float I2  = satf(fmaf(DT_, Iv1, I1s));
                    float uI1 = tanh500(C4_*sigf(C3_*M1r));
                    float Iv2 = satf(fmaf(KIv, Iv1, fmaf(KIu, uI1, -KIx*I1s)));
                    // E chain, step h
                    int h0 = 2*kb;
                    float u0  = uslab[h0*N_+t];
                    float ne0 = neslab[h0*N_+t];
                    float rE0 = fmaf(STD_, ne0, G_*(LEd0 - rowsum*E)) + C2_*sigf(C1_*M);
                    float uE0 = fmaf(K_, u0, tanh500(rE0));
                    float Ev1 = satf(fmaf(KEv, Ev, fmaf(KEu, uE0, -KEx*E)));
                    float E2  = satf(fmaf(DT_, Ev1, E1s));
                    // E chain, step h+1
                    float u1  = uslab[(h0+1)*N_+t];
                    float ne1 = neslab[(h0+1)*N_+t];
                    float rE1 = fmaf(STD_, ne1, G_*(LEd1 - rowsum*E1s)) + C2_*sigf(C1_*M1r);
                    float uE1 = fmaf(K_, u1, tanh500(rE1));
                    float Ev2 = satf(fmaf(KEv, Ev1, fmaf(KEu, uE1, -KEx*E1s)));
                    // rotate carries
                    M=M2; M1r=M3; Mv=Mv2;
                    I=I2; Iv=Iv2;
                    E=E2; Ev=Ev2;
                }
                // last sync per outer dropped: boundary __syncthreads orders
                // block 9's pair reads before next outer's block-0 write.
                if (kb < 9) ROW_SYNC();
            }
            if (isr){ histT[t*HS_ + smod] = M; emi[t] = E - I; }
        } else {
            // ---- free gather waves: flat 50-entry gather, no step sync ----
            float acc = 0.f;
            {
                const float4* t4 = (const float4*)(tab + (size_t)gf*EPT);
                #pragma unroll 5
                for (int m=0;m<EPT/2;++m){
                    float4 ee = t4[m];
                    unsigned um0 = __float_as_uint(ee.y);
                    int c0 = ts - (int)(um0>>16); if (c0<0) c0 += HD_;
                    acc = fmaf(ee.x, histT[(um0&0xFFFFu)*HS_ + c0], acc);
                    unsigned um1 = __float_as_uint(ee.w);
                    int c1 = ts - (int)(um1>>16); if (c1<0) c1 += HD_;
                    acc = fmaf(ee.z, histT[(um1&0xFFFFu)*HS_ + c1], acc);
                }
            }
            led_part[(gf&3)*N_ + (gf>>2)] = acc;
            if (gf < NG_-NFREE){                    // 32 threads: 2nd unit
                const int u1 = NFREE + gf;
                float acc1 = 0.f;
                const float4* t4 = (const float4*)(tab + (size_t)u1*EPT);
                #pragma unroll 5
                for (int m=0;m<EPT/2;++m){
                    float4 ee = t4[m];
                    unsigned um0 = __float_as_uint(ee.y);
                    int c0 = ts - (int)(um0>>16); if (c0<0) c0 += HD_;
                    acc1 = fmaf(ee.x, histT[(um0&0xFFFFu)*HS_ + c0], acc1);
                    unsigned um1 = __float_as_uint(ee.w);
                    int c1 = ts - (int)(um1>>16); if (c1<0) c1 += HD_;
                    acc1 = fmaf(ee.z, histT[(um1&0xFFFFu)*HS_ + c1], acc1);
                }
                led_part[(u1&3)*N_ + (u1>>2)] = acc1;
            }
            // slab loads for s+1 into registers (LDS write deferred past A)
            int sn = s+1; if (sn >= B_) sn = B_-1;
            #pragma unroll
            for (int r=0;r<5;++r){
                su_r[r] = input[goffM[r] + sn];
                sn_r[r] = noise_in[(goffM[r] + sn)*3];
            }
            if (has6){
                su_r[5] = input[goffM[5] + sn];
                sn_r[5] = noise_in[(goffM[5] + sn)*3];
            }
        }
        __syncthreads();                            // boundary A
        if (isr){
            // d==1 term for s+1: M_end(s) = .x of mpair buffer 0 (10 blocks
            // per outer -> block 9 wrote mpair[0]; next block 0 reads it)
            float v = led_part[t]+led_part[N_+t]+led_part[2*N_+t]+led_part[3*N_+t];
            #pragma unroll
            for (int k=0;k<UNR;++k)
                v = fmaf(d1w_l[k*N_+t], mpair[d1j_l[k*N_+t]].x, v);
            for (int k=UNR;k<cnt1;++k)
                v = fmaf(d1w_l[k*N_+t], mpair[d1j_l[k*N_+t]].x, v);
            ledst = v;
        }
        if (t >= RW_){
            // slab LDS writes AFTER A (rows done reading slab for s)
            #pragma unroll
            for (int r=0;r<5;++r){
                uslab[sidxM[r]]  = su_r[r];
                neslab[sidxM[r]] = sn_r[r];
            }
            if (has6){ uslab[sidxM[5]] = su_r[5]; neslab[sidxM[5]] = sn_r[5]; }
        }
        {   // eeg (all threads)
            int o = t>>4, l = t&15;
            float il = frcp(lmrs[o]);
            float a2 = 0.f;
            for (int j=l;j<N_;j+=16)
                a2 = fmaf(fmaf(lm[o*N_+j], il, -colmean[j]), emi[j], a2);
            a2 += __shfl_down(a2,8,16); a2 += __shfl_down(a2,4,16);
            a2 += __shfl_down(a2,2,16); a2 += __shfl_down(a2,1,16);
            if (l==0) out[o*B_+s] = fmaf(CY0_, a2, -Y0_);
        }
        smod = ts;
        __syncthreads();                            // boundary B
    }

#undef ROW_SYNC

    // final state (all carries are exactly state(8000))
    if (isr){
        float* cs = out + OUT_*B_ + t*6;
        cs[0]=M; cs[1]=E; cs[2]=I; cs[3]=Mv; cs[4]=Ev; cs[5]=Iv;
    }
}

} // namespace

extern "C" void kernel_launch(void* const* d_in, const int* in_sizes, int n_in,
                              void* d_out, int out_size, void* d_ws, size_t ws_size,
                              hipStream_t stream)
{
    const float* input    = (const float*)d_in[0];
    const float* noise_in = (const float*)d_in[1];
    const float* hx   = (const float*)d_in[3];
    const float* hEin = (const float*)d_in[4];
    const float* wbb  = (const float*)d_in[5];
    const float* lm   = (const float*)d_in[6];
    const float* sc   = (const float*)d_in[7];
    const int*   dist = (const int*)d_in[8];
    float* out = (float*)d_out;
    float2* tab = (float2*)((char*)d_ws + 1024);   // 40000 x 8B = 320KB

    hipLaunchKernelGGL(jansen_kernel, dim3(1), dim3(NT_), 0, stream,
                       input, noise_in, hx, hEin, wbb, lm, sc, dist, out, tab);
}